// Round 4
// baseline (167.833 us; speedup 1.0000x reference)
//
#include <hip/hip_runtime.h>
#include <hip/hip_bf16.h>

// out[b,o] = sum_i x[b,i]*w[o,i] + bias[o]; M=4096, N=2048, K=2048, fp32 io.
// R10: kill the separate cvt pass. R6/R8/R9 all land 42-43.7us gemm regardless
// of schedule => schedule is not the lever. dur_us ~= gemm + cvt(12.5) + ~77us
// of harness poison fills/gaps. Controllable remainder = cvt + launch gap.
// This kernel reads fp32 x,w directly and converts to bf16 during staging:
//   reg-staged: 24x global_load_dwordx4 -> f2bf_rne (bit-identical to old
//   cvt_both) -> 12x ds_write_b128, producing the IDENTICAL LDS image the
//   global_load_lds path produced (slot = chunk ^ (row&7) XOR swizzle).
// T14 split: loads issued in phase 0, vmcnt(0) tie-asm after phase-1 MFMA
// (12 "+v" operands pin the cvt below the wait); asm s_barrier with memory
// clobber pins load issue. 2-buffer LDS (96KB) + 128KB epilogue scratch.
// Keeps R9's verified kc-split compute/epilogue (8 waves = 4 pos x 2 K-slices,
// acc[8][4], XCD block swizzle, setprio around MFMA clusters).

#define M_DIM 4096
#define N_DIM 2048
#define K_DIM 2048
#define BM 256
#define BN 128
#define BK 64
#define NT (K_DIM / BK)   // 32 K-tiles
#define ASZ (BM * BK)     // 16384 ushort = 32 KB
#define BSZ (BN * BK)     // 8192 ushort = 16 KB

typedef unsigned short ushort_t;
typedef __attribute__((ext_vector_type(8))) short short8;      // 8 bf16 (A/B frag)
typedef __attribute__((ext_vector_type(4))) float float4v;     // C/D frag + loads
typedef __attribute__((ext_vector_type(8))) unsigned short ushort8;

// fp32 -> bf16 RNE, bit-identical to the previous cvt_both pipeline.
__device__ __forceinline__ unsigned short f2bf_rne(float f) {
    unsigned int u = __builtin_bit_cast(unsigned int, f);
    u += 0x7FFFu + ((u >> 16) & 1u);
    return (unsigned short)(u >> 16);
}

__device__ __forceinline__ ushort8 pack8(float4v a, float4v b) {
    ushort8 r;
    r[0] = f2bf_rne(a[0]); r[1] = f2bf_rne(a[1]);
    r[2] = f2bf_rne(a[2]); r[3] = f2bf_rne(a[3]);
    r[4] = f2bf_rne(b[0]); r[5] = f2bf_rne(b[1]);
    r[6] = f2bf_rne(b[2]); r[7] = f2bf_rne(b[3]);
    return r;
}

#define BARRIER() asm volatile("s_barrier" ::: "memory")

// ---------------- fused bf16 MFMA GEMM, C = f(X) * f(W)^T + bias ----------------
// X: [M,K] fp32 row-major, W: [N,K] fp32 row-major (converted in-kernel).
// Block: 256x128 tile, 512 threads = 8 waves = 4 positions (2x2 of 128x64)
// x 2 K-slices (wave ks handles K-half ks of each BK=64 tile).
__global__ void __launch_bounds__(512, 1)
gemm_fused(const float* __restrict__ x,
           const float* __restrict__ w,
           const float* __restrict__ bias,
           float* __restrict__ out) {
    __shared__ ushort_t lds[65536];          // 128 KB (staging 96 KB / epi 128 KB)
    ushort_t* ldsA = lds;                    // 2 x 32 KB double-buffered A tiles
    ushort_t* ldsB = lds + 2 * ASZ;          // 2 x 16 KB double-buffered B tiles

    const int tid  = threadIdx.x;
    const int wave = tid >> 6;
    const int lane = tid & 63;
    const int quad = lane >> 4;    // 0..3
    const int lrow = lane & 15;    // 0..15

    // XCD-aware swizzle: 256 blocks, 8 XCDs, nwg%8==0 -> simple bijection.
    const int swzb = ((int)blockIdx.x & 7) * 32 + ((int)blockIdx.x >> 3);
    const int rowBase = (swzb >> 4) * BM;   // 16 M-blocks
    const int colBase = (swzb & 15) * BN;   // 16 N-blocks

    const int pos  = wave & 3;           // tile position: 2(row) x 2(col)
    const int ks   = wave >> 2;          // K-slice: 0 -> K[0,32), 1 -> K[32,64)
    const int posR = (pos >> 1) * 128;   // 0 or 128
    const int posC = (pos & 1) * 64;     // 0 or 64

    // ---- staging geometry: rows are 8 bf16-chunks of 16B (= 32B fp32).
    // Thread handles chunk schunk=(tid&7)^(srow&7) of rows {64j+srow};
    // LDS dest slot = schunk ^ (row&7) = tid&7 -> ushort addr 4096j + 8*tid
    // (identical image to the old global_load_lds layout). ----
    const int srow   = tid >> 3;                       // 0..63
    const int schunk = (tid & 7) ^ (srow & 7);
    const float* fA[4];
    const float* fB[2];
#pragma unroll
    for (int j = 0; j < 4; j++)
        fA[j] = x + (size_t)(rowBase + 64 * j + srow) * K_DIM + schunk * 8;
#pragma unroll
    for (int j = 0; j < 2; j++)
        fB[j] = w + (size_t)(colBase + 64 * j + srow) * K_DIM + schunk * 8;
    const int wadr = 8 * tid;   // ushort units within a tile buffer

    // ---- fragment read swizzle: chunk c = ks*4+quad at slot c ^ (lrow&7);
    // ushort offset = slot*8 = (quad^(lrow&7))*8 ^ ks*32 (bits disjoint). ----
    const int swzr = ((quad ^ (lrow & 7)) * 8) ^ (ks * 32);

    float4v acc[8][4] = {};   // 128x64 per-wave tile (this wave's K-half)

    // ---- prologue: stage tile 0 into buf 0 synchronously ----
    {
#pragma unroll
        for (int j = 0; j < 4; j++) {
            float4v a = *(const float4v*)(fA[j]);
            float4v b = *(const float4v*)(fA[j] + 4);
            *(ushort8*)(ldsA + j * 4096 + wadr) = pack8(a, b);
        }
#pragma unroll
        for (int j = 0; j < 2; j++) {
            float4v a = *(const float4v*)(fB[j]);
            float4v b = *(const float4v*)(fB[j] + 4);
            *(ushort8*)(ldsB + j * 4096 + wadr) = pack8(a, b);
        }
#pragma unroll
        for (int j = 0; j < 4; j++) fA[j] += BK;
#pragma unroll
        for (int j = 0; j < 2; j++) fB[j] += BK;
    }
    __syncthreads();

    int cur = 0;
    for (int t = 0; t < NT; ++t) {
        const ushort_t* aT = ldsA + cur * ASZ + (posR + lrow) * BK;
        const ushort_t* bT = ldsB + cur * BSZ + (posC + lrow) * BK;
        ushort_t* sA = ldsA + (cur ^ 1) * ASZ;
        ushort_t* sB = ldsB + (cur ^ 1) * BSZ;
        const bool stg = (t + 1 < NT);

        // ======== phase 0: ds_read frags + issue next tile's global loads ====
        short8 af[4], bf[4];
#pragma unroll
        for (int mi = 0; mi < 4; mi++) af[mi] = *(const short8*)(aT + mi * 1024 + swzr);
#pragma unroll
        for (int ni = 0; ni < 4; ni++) bf[ni] = *(const short8*)(bT + ni * 1024 + swzr);
        float4v la[8], lb[4];
        if (stg) {
#pragma unroll
            for (int j = 0; j < 4; j++) {
                la[2 * j]     = *(const float4v*)(fA[j]);
                la[2 * j + 1] = *(const float4v*)(fA[j] + 4);
            }
#pragma unroll
            for (int j = 0; j < 2; j++) {
                lb[2 * j]     = *(const float4v*)(fB[j]);
                lb[2 * j + 1] = *(const float4v*)(fB[j] + 4);
            }
        }
        BARRIER();   // loads issued above cannot sink past ("memory")
        __builtin_amdgcn_s_setprio(1);
#pragma unroll
        for (int mi = 0; mi < 4; mi++)
#pragma unroll
            for (int ni = 0; ni < 4; ni++)
                acc[mi][ni] = __builtin_amdgcn_mfma_f32_16x16x32_bf16(
                    af[mi], bf[ni], acc[mi][ni], 0, 0, 0);
        __builtin_amdgcn_s_setprio(0);
        BARRIER();

        // ======== phase 1: A-rows 4..7 (bf reused) ========
        short8 ag[4];
#pragma unroll
        for (int mi = 0; mi < 4; mi++) ag[mi] = *(const short8*)(aT + (mi + 4) * 1024 + swzr);
        BARRIER();
        __builtin_amdgcn_s_setprio(1);
#pragma unroll
        for (int mi = 0; mi < 4; mi++)
#pragma unroll
            for (int ni = 0; ni < 4; ni++)
                acc[mi + 4][ni] = __builtin_amdgcn_mfma_f32_16x16x32_bf16(
                    ag[mi], bf[ni], acc[mi + 4][ni], 0, 0, 0);
        __builtin_amdgcn_s_setprio(0);

        // ---- tile boundary: wait for staged loads (tie pins cvt below the
        // wait), convert, publish into the other buffer. ----
        if (stg) {
            asm volatile("s_waitcnt vmcnt(0)"
                         : "+v"(la[0]), "+v"(la[1]), "+v"(la[2]), "+v"(la[3]),
                           "+v"(la[4]), "+v"(la[5]), "+v"(la[6]), "+v"(la[7]),
                           "+v"(lb[0]), "+v"(lb[1]), "+v"(lb[2]), "+v"(lb[3])
                         :: "memory");
#pragma unroll
            for (int j = 0; j < 4; j++)
                *(ushort8*)(sA + j * 4096 + wadr) = pack8(la[2 * j], la[2 * j + 1]);
#pragma unroll
            for (int j = 0; j < 2; j++)
                *(ushort8*)(sB + j * 4096 + wadr) = pack8(lb[2 * j], lb[2 * j + 1]);
#pragma unroll
            for (int j = 0; j < 4; j++) fA[j] += BK;
#pragma unroll
            for (int j = 0; j < 2; j++) fB[j] += BK;
        }
        BARRIER();
        cur ^= 1;
    }

    // ---- epilogue: reduce the two K-slices via LDS, then write out.
    // acc frag layout (harness-verified): col = lane&15, row = quad*4 + reg.
    // LDS scratch: pos*32KB + (mi*4+ni)*1KB + lane*16B; 128 KB total. ----
    float* fl = (float*)lds;
    __syncthreads();   // all staged-tile reads done; drains lgkm
    if (ks == 1) {
#pragma unroll
        for (int mi = 0; mi < 8; mi++)
#pragma unroll
            for (int ni = 0; ni < 4; ni++)
                *(float4v*)(fl + pos * 8192 + (mi * 4 + ni) * 256 + lane * 4) = acc[mi][ni];
    }
    __syncthreads();
    if (ks == 0) {
#pragma unroll
        for (int ni = 0; ni < 4; ni++) {
            const int col = colBase + posC + ni * 16 + lrow;
            const float bv = bias[col];
#pragma unroll
            for (int mi = 0; mi < 8; mi++) {
                const int row0 = rowBase + posR + mi * 16 + quad * 4;
                float4v p = *(const float4v*)(fl + pos * 8192 + (mi * 4 + ni) * 256 + lane * 4);
                float4v v = acc[mi][ni] + p;
#pragma unroll
                for (int i = 0; i < 4; i++)
                    out[(size_t)(row0 + i) * N_DIM + col] = v[i] + bv;
            }
        }
    }
}

extern "C" void kernel_launch(void* const* d_in, const int* in_sizes, int n_in,
                              void* d_out, int out_size, void* d_ws, size_t ws_size,
                              hipStream_t stream) {
    const float* x    = (const float*)d_in[0];   // [4096, 2048]
    const float* w    = (const float*)d_in[1];   // [2048, 2048]
    const float* bias = (const float*)d_in[2];   // [2048]
    float* out = (float*)d_out;                  // [4096, 2048]
    (void)d_ws; (void)ws_size;                   // workspace no longer used

    gemm_fused<<<(M_DIM / BM) * (N_DIM / BN), 512, 0, stream>>>(x, w, bias, out);
}